// Round 1
// 483.971 us; speedup vs baseline: 1.1402x; 1.1402x over previous
//
#include <hip/hip_runtime.h>
#include <hip/hip_bf16.h>
#include <stdint.h>

#define IN_F 4096
#define OUT_F 4096
#define RANK 16
#define LORA_SCALE 2.0f

typedef __attribute__((ext_vector_type(8))) short short8;
typedef __attribute__((ext_vector_type(4))) float f32x4;
typedef __attribute__((ext_vector_type(16))) float f32x16;

__device__ __constant__ float NF4_CODE[16] = {
    -1.0f, -0.6961928009986877f, -0.5250730514526367f, -0.39491748809814453f,
    -0.28444138169288635f, -0.18477343022823334f, -0.09105003625154495f, 0.0f,
    0.07958029955625534f, 0.16093020141124725f, 0.24611230194568634f,
    0.33791524171829224f, 0.44070982933044434f, 0.5626170039176941f,
    0.7229568362236023f, 1.0f};

__device__ __forceinline__ short bf16_rne(float f) {
    uint32_t u = __builtin_bit_cast(uint32_t, f);
    u += 0x7fffu + ((u >> 16) & 1u);
    return (short)(u >> 16);
}

__device__ __forceinline__ void load_lds16(const short* g, short* l) {
    __builtin_amdgcn_global_load_lds(
        (const __attribute__((address_space(1))) void*)g,
        (__attribute__((address_space(3))) void*)l, 16, 0, 0);
}

// ---------------------------------------------------------------------------
// Fused prep (one launch):
//   blocks [0,4096):       W_eff[o][i] = NF4[codes]*absmax + 2*(Wa@Wb)^T  (bf16)
//   blocks [4096,4096+Nc): x fp32 -> bf16 cast, 2048 elems/block
// ---------------------------------------------------------------------------
__global__ __launch_bounds__(256)
void prep_kernel(const int* __restrict__ codes, const float* __restrict__ am,
                 const float* __restrict__ Wa, const float* __restrict__ Wb,
                 const float* __restrict__ x, short* __restrict__ Weff,
                 short* __restrict__ xb)
{
    const int tid = threadIdx.x;

    if (blockIdx.x >= 4096) {
        const size_t i = (size_t)(blockIdx.x - 4096) * 256 + tid;
        const f32x4* xv = (const f32x4*)x;
        f32x4 a = xv[2 * i], b = xv[2 * i + 1];
        short8 o;
        o[0] = bf16_rne(a[0]); o[1] = bf16_rne(a[1]);
        o[2] = bf16_rne(a[2]); o[3] = bf16_rne(a[3]);
        o[4] = bf16_rne(b[0]); o[5] = bf16_rne(b[1]);
        o[6] = bf16_rne(b[2]); o[7] = bf16_rne(b[3]);
        ((short8*)xb)[i] = o;
        return;
    }

    __shared__ float WaT[RANK * 64];   // [r][i_local]
    __shared__ float Wbs[RANK * 64];   // [r][o_local]

    const int iBase = (blockIdx.x & 63) * 64;
    const int oBase = (blockIdx.x >> 6) * 64;

    {
        f32x4 v = *(const f32x4*)(Wa + (size_t)iBase * RANK + tid * 4);
        #pragma unroll
        for (int j = 0; j < 4; j++) {
            int e = tid * 4 + j;                 // e = i_local*16 + r
            WaT[(e & 15) * 64 + (e >> 4)] = v[j];
        }
        int r = tid >> 4, c = (tid & 15) * 4;
        f32x4 w = *(const f32x4*)(Wb + (size_t)r * OUT_F + oBase + c);
        *(f32x4*)&Wbs[r * 64 + c] = w;
    }
    __syncthreads();

    #pragma unroll
    for (int p = 0; p < 2; p++) {
        const int g  = tid + p * 256;   // 512 groups: 64 o-rows x 8 i-groups
        const int o  = g >> 3;
        const int ig = (g & 7) * 8;
        const float amax = am[(size_t)(oBase + o) * (IN_F / 64) + (iBase >> 6)];

        const int4* cp = (const int4*)(codes + (size_t)(oBase + o) * IN_F + iBase + ig);
        int4 c0 = cp[0], c1 = cp[1];
        int cc[8] = {c0.x, c0.y, c0.z, c0.w, c1.x, c1.y, c1.z, c1.w};

        float acc[8] = {0, 0, 0, 0, 0, 0, 0, 0};
        #pragma unroll
        for (int r = 0; r < RANK; r++) {
            float wb = Wbs[r * 64 + o];
            f32x4 a0 = *(const f32x4*)&WaT[r * 64 + ig];
            f32x4 a1 = *(const f32x4*)&WaT[r * 64 + ig + 4];
            acc[0] += a0[0] * wb;  acc[1] += a0[1] * wb;
            acc[2] += a0[2] * wb;  acc[3] += a0[3] * wb;
            acc[4] += a1[0] * wb;  acc[5] += a1[1] * wb;
            acc[6] += a1[2] * wb;  acc[7] += a1[3] * wb;
        }

        short8 out;
        #pragma unroll
        for (int j = 0; j < 8; j++)
            out[j] = bf16_rne(NF4_CODE[cc[j] & 15] * amax + LORA_SCALE * acc[j]);
        *(short8*)(Weff + (size_t)(oBase + o) * IN_F + iBase + ig) = out;
    }
}

// ---------------------------------------------------------------------------
// Legacy 128x128 GEMM, kept only as the small-workspace fallback path.
// ---------------------------------------------------------------------------
template<bool ABF16>
__global__ __launch_bounds__(256)
void gemm32(const void* __restrict__ Ain, const short* __restrict__ Bt,
            float* __restrict__ C)
{
    __shared__ __align__(16) short lds[16384];  // A:[0,8192) B:[8192,16384)
    short* sA = lds;
    short* sB = lds + 8192;

    const int tid  = threadIdx.x;
    const int lane = tid & 63;
    const int wave = tid >> 6;
    const int mBase = blockIdx.y * 128;
    const int nBase = blockIdx.x * 128;
    const int wm = (wave >> 1) * 64;
    const int wn = (wave & 1) * 64;

    const int srow = tid >> 3;
    const int scol = ((tid & 7) ^ (srow & 7)) * 8;

    const short* gA[4]; const float* fA[4]; const short* gB[4];
    #pragma unroll
    for (int p = 0; p < 4; p++) {
        if constexpr (ABF16)
            gA[p] = (const short*)Ain + (size_t)(mBase + p * 32 + srow) * IN_F + scol;
        else
            fA[p] = (const float*)Ain + (size_t)(mBase + p * 32 + srow) * IN_F + scol;
        gB[p] = Bt + (size_t)(nBase + p * 32 + srow) * IN_F + scol;
    }
    short* dA[4]; short* dB[4];
    #pragma unroll
    for (int p = 0; p < 4; p++) {
        dA[p] = sA + (p * 256 + tid) * 8;
        dB[p] = sB + (p * 256 + tid) * 8;
    }

    const int l31 = lane & 31;
    const int h   = lane >> 5;
    const int r7  = lane & 7;
    int xo[4];
    #pragma unroll
    for (int s = 0; s < 4; s++) xo[s] = ((s * 2 + h) ^ r7) * 8;
    const int rA0 = (wm + l31) * 64, rA1 = rA0 + 32 * 64;
    const int rB0 = (wn + l31) * 64, rB1 = rB0 + 32 * 64;

    f32x16 acc[2][2];
    #pragma unroll
    for (int i = 0; i < 2; i++)
        #pragma unroll
        for (int j = 0; j < 2; j++)
            #pragma unroll
            for (int r = 0; r < 16; r++)
                acc[i][j][r] = 0.f;

    for (int k0 = 0; k0 < IN_F; k0 += 64) {
        if constexpr (ABF16) {
            #pragma unroll
            for (int p = 0; p < 4; p++) load_lds16(gA[p] + k0, dA[p]);
        } else {
            #pragma unroll
            for (int p = 0; p < 4; p++) {
                const float* s0 = fA[p] + k0;
                f32x4 v0 = *(const f32x4*)s0;
                f32x4 v1 = *(const f32x4*)(s0 + 4);
                short8 o;
                #pragma unroll
                for (int j = 0; j < 4; j++) {
                    o[j] = bf16_rne(v0[j]); o[j + 4] = bf16_rne(v1[j]);
                }
                *(short8*)dA[p] = o;
            }
        }
        #pragma unroll
        for (int p = 0; p < 4; p++) load_lds16(gB[p] + k0, dB[p]);
        __syncthreads();

        #pragma unroll
        for (int s = 0; s < 4; s++) {
            short8 a0 = *(const short8*)(sA + rA0 + xo[s]);
            short8 a1 = *(const short8*)(sA + rA1 + xo[s]);
            short8 b0 = *(const short8*)(sB + rB0 + xo[s]);
            short8 b1 = *(const short8*)(sB + rB1 + xo[s]);
            acc[0][0] = __builtin_amdgcn_mfma_f32_32x32x16_bf16(a0, b0, acc[0][0], 0, 0, 0);
            acc[0][1] = __builtin_amdgcn_mfma_f32_32x32x16_bf16(a0, b1, acc[0][1], 0, 0, 0);
            acc[1][0] = __builtin_amdgcn_mfma_f32_32x32x16_bf16(a1, b0, acc[1][0], 0, 0, 0);
            acc[1][1] = __builtin_amdgcn_mfma_f32_32x32x16_bf16(a1, b1, acc[1][1], 0, 0, 0);
        }
        __syncthreads();
    }

    #pragma unroll
    for (int mi = 0; mi < 2; mi++) {
        #pragma unroll
        for (int ni = 0; ni < 2; ni++) {
            const int col  = nBase + wn + ni * 32 + l31;
            const int rowb = mBase + wm + mi * 32 + 4 * h;
            #pragma unroll
            for (int r = 0; r < 16; r++) {
                const int row = rowb + (r & 3) + 8 * (r >> 2);
                C[(size_t)row * OUT_F + col] = acc[mi][ni][r];
            }
        }
    }
}

// ---------------------------------------------------------------------------
// 256x256 8-phase GEMM (m201-class schedule), C = A * Bt^T, bf16 in / f32 out.
// 512 thr = 8 waves (2M x 4N). BK=64. LDS 128 KiB = 2 dbuf x (A 256x64 + B
// 256x64). Each K-tile split in halves: Ah0=rows 0..127, Ah1=128..255 (same
// for B cols). Per-wave 128x64 output interleaved across halves:
//   m-quad0 rows = wm*64..+63 (Ah0), m-quad1 = 128+wm*64..+63 (Ah1)
//   n-quad0 cols = wn*32..+31 (Bh0), n-quad1 = 128+wn*32..+31 (Bh1)
// so each stored half frees after exactly one phase -> 3-half-tile prefetch
// depth with counted vmcnt(6), never drained to 0 in the loop (T3+T4).
// LDS swizzle: slot(row,c) holds global chunk c^(row&7); ds_read lanes 0-15
// spread over 8 x 16B slots -> 2-way (free).  Source pre-swizzled so
// global_load_lds dest stays linear (both-sides rule, m104/m231).
// Fragment maps (16x16x32 bf16, verified m89/m91): A/B row=lane&15,
// k=(lane>>4)*8+j; C/D col=lane&15, row=(lane>>4)*4+reg.
// ---------------------------------------------------------------------------
#define FENCE() __builtin_amdgcn_sched_barrier(0)
#define BARRIER() do { asm volatile("" ::: "memory"); FENCE(); \
    __builtin_amdgcn_s_barrier(); FENCE(); asm volatile("" ::: "memory"); } while(0)
#define WAIT_LGKM0() do { asm volatile("s_waitcnt lgkmcnt(0)" ::: "memory"); FENCE(); } while(0)
#define WAIT_VM6() do { asm volatile("s_waitcnt vmcnt(6)" ::: "memory"); FENCE(); } while(0)

#define STAGE_A(BUF, H, T) do { \
    const short* _g = gA + (size_t)(H) * 128 * IN_F + (T) * 64; \
    load_lds16(_g,                   lds + (BUF)*32768 + (H)*8192 + tid*8); \
    load_lds16(_g + (size_t)64*IN_F, lds + (BUF)*32768 + (H)*8192 + 4096 + tid*8); \
} while(0)

#define STAGE_B(BUF, H, T) do { \
    const short* _g = gB + (size_t)(H) * 128 * IN_F + (T) * 64; \
    load_lds16(_g,                   lds + (BUF)*32768 + 16384 + (H)*8192 + tid*8); \
    load_lds16(_g + (size_t)64*IN_F, lds + (BUF)*32768 + 16384 + (H)*8192 + 4096 + tid*8); \
} while(0)

#define READ_A(BUF, MQ) do { \
    const short* _s = lds + (BUF)*32768 + (MQ)*8192; \
    _Pragma("unroll") \
    for (int mf = 0; mf < 4; ++mf) { \
        const int row = wm*64 + mf*16 + l15; \
        const short* _r = _s + row*64; \
        const int rs = row & 7; \
        afr[mf][0] = *(const short8*)(_r + ((kl     ) ^ rs) * 8); \
        afr[mf][1] = *(const short8*)(_r + ((kl | 4) ^ rs) * 8); \
    } \
} while(0)

#define READ_B(BUF, NQ) do { \
    const short* _s = lds + (BUF)*32768 + 16384 + (NQ)*8192; \
    _Pragma("unroll") \
    for (int nf = 0; nf < 2; ++nf) { \
        const int row = wn*32 + nf*16 + l15; \
        const short* _r = _s + row*64; \
        const int rs = row & 7; \
        bfr[nf][0] = *(const short8*)(_r + ((kl     ) ^ rs) * 8); \
        bfr[nf][1] = *(const short8*)(_r + ((kl | 4) ^ rs) * 8); \
    } \
} while(0)

#define MFMA_QUAD(MQ, NQ) do { \
    _Pragma("unroll") \
    for (int ks = 0; ks < 2; ++ks) \
    _Pragma("unroll") \
    for (int mf = 0; mf < 4; ++mf) \
    _Pragma("unroll") \
    for (int nf = 0; nf < 2; ++nf) \
        acc[MQ][NQ][mf][nf] = __builtin_amdgcn_mfma_f32_16x16x32_bf16( \
            afr[mf][ks], bfr[nf][ks], acc[MQ][NQ][mf][nf], 0, 0, 0); \
} while(0)

#define PHASE(RDA, RDB, BUF, MQ, NQ, STAGE_STMT, VM_STMT) do { \
    if (RDA) READ_A(BUF, MQ); \
    if (RDB) READ_B(BUF, NQ); \
    STAGE_STMT; \
    BARRIER(); \
    WAIT_LGKM0(); \
    __builtin_amdgcn_s_setprio(1); \
    MFMA_QUAD(MQ, NQ); \
    __builtin_amdgcn_s_setprio(0); \
    VM_STMT; \
    BARRIER(); \
} while(0)

__global__ __launch_bounds__(512, 2)
void gemm256(const short* __restrict__ A, const short* __restrict__ Bt,
             float* __restrict__ C)
{
    __shared__ __align__(16) short lds[65536];   // 128 KiB

    const int tid  = threadIdx.x;
    const int lane = tid & 63;
    const int wave = tid >> 6;
    const int wm  = wave >> 2;       // 0..1
    const int wn  = wave & 3;        // 0..3
    const int l15 = lane & 15;
    const int kl  = lane >> 4;       // 0..3

    // bijective XCD swizzle (grid is a multiple of 8)
    const int nwg = gridDim.x;
    int bid = blockIdx.x;
    bid = (bid & 7) * (nwg >> 3) + (bid >> 3);
    const int by = bid >> 4;                 // gridN = OUT_F/256 = 16
    const int bx = bid & 15;
    const int mBase = by * 256;
    const int nBase = bx * 256;

    // staging: thread t covers row (l*64 + t>>3) of a 128-row half, chunk
    // (t&7); source pre-swizzled by ^(row&7); LDS dest linear (t*16 B).
    const int rt = tid >> 3;
    const int sw = ((tid & 7) ^ (rt & 7)) * 8;
    const short* gA = A  + (size_t)(mBase + rt) * IN_F + sw;
    const short* gB = Bt + (size_t)(nBase + rt) * IN_F + sw;

    f32x4 acc[2][2][4][2];
    #pragma unroll
    for (int i = 0; i < 2; ++i)
    #pragma unroll
    for (int j = 0; j < 2; ++j)
    #pragma unroll
    for (int m = 0; m < 4; ++m)
    #pragma unroll
    for (int n = 0; n < 2; ++n)
    #pragma unroll
    for (int r = 0; r < 4; ++r)
        acc[i][j][m][n][r] = 0.f;

    short8 afr[4][2];
    short8 bfr[2][2];

    // prologue: tile0 all 4 halves (buf0), tile1 first 3 halves (buf1)
    STAGE_A(0, 0, 0); STAGE_B(0, 1, 0); STAGE_A(0, 1, 0); STAGE_B(0, 0, 0);
    STAGE_A(1, 0, 1); STAGE_B(1, 1, 1); STAGE_A(1, 1, 1);
    WAIT_VM6();            // 14 issued, wait to 6 -> tile0 fully landed
    BARRIER();

    const int NT = IN_F / 64;        // 64 K-tiles
    #pragma unroll 1
    for (int it = 0; it < NT / 2; ++it) {
        const int T  = 2 * it;
        const int t2 = (T + 2 < NT) ? (T + 2) : (NT - 1);   // clamped (dead data)
        const int t3 = (T + 3 < NT) ? (T + 3) : (NT - 1);
        // tile T in buf0, tile T+1 in buf1; stage slot = half freed last phase
        PHASE(1, 1, 0, 0, 0, STAGE_B(1, 0, T + 1), (void)0);
        PHASE(0, 1, 0, 0, 1, STAGE_A(0, 0, t2),    (void)0);
        PHASE(1, 0, 0, 1, 1, STAGE_B(0, 1, t2),    (void)0);
        PHASE(0, 1, 0, 1, 0, STAGE_A(0, 1, t2),    WAIT_VM6());
        PHASE(1, 1, 1, 0, 0, STAGE_B(0, 0, t2),    (void)0);
        PHASE(0, 1, 1, 0, 1, STAGE_A(1, 0, t3),    (void)0);
        PHASE(1, 0, 1, 1, 1, STAGE_B(1, 1, t3),    (void)0);
        PHASE(0, 1, 1, 1, 0, STAGE_A(1, 1, t3),    WAIT_VM6());
    }

    // epilogue: C/D layout col=lane&15, row=(lane>>4)*4+reg
    #pragma unroll
    for (int mq = 0; mq < 2; ++mq)
    #pragma unroll
    for (int nq = 0; nq < 2; ++nq)
    #pragma unroll
    for (int mf = 0; mf < 4; ++mf) {
        const int row0 = mBase + mq * 128 + wm * 64 + mf * 16 + kl * 4;
        #pragma unroll
        for (int nf = 0; nf < 2; ++nf) {
            const int col = nBase + nq * 128 + wn * 32 + nf * 16 + l15;
            float* cp = C + (size_t)row0 * OUT_F + col;
            #pragma unroll
            for (int r = 0; r < 4; ++r)
                cp[(size_t)r * OUT_F] = acc[mq][nq][mf][nf][r];
        }
    }
}

// ---------------------------------------------------------------------------
extern "C" void kernel_launch(void* const* d_in, const int* in_sizes, int n_in,
                              void* d_out, int out_size, void* d_ws, size_t ws_size,
                              hipStream_t stream)
{
    const float* x     = (const float*)d_in[0];
    const int*   codes = (const int*)d_in[1];
    const float* am    = (const float*)d_in[2];
    const float* Wa    = (const float*)d_in[3];
    const float* Wb    = (const float*)d_in[4];
    float* out = (float*)d_out;

    const int M = in_sizes[0] / IN_F;   // 8192 tokens

    short* Weff = (short*)d_ws;                          // OUT_F*IN_F bf16
    short* xb   = Weff + (size_t)OUT_F * IN_F;           // M*IN_F bf16
    const size_t need_full =
        ((size_t)OUT_F * IN_F + (size_t)M * IN_F) * sizeof(short);

    if (ws_size >= need_full) {
        const int castBlocks = (M * IN_F / 8) / 256;
        prep_kernel<<<4096 + castBlocks, 256, 0, stream>>>(
            codes, am, Wa, Wb, x, Weff, xb);
        if ((M & 255) == 0) {
            gemm256<<<dim3((OUT_F / 256) * (M / 256)), 512, 0, stream>>>(
                xb, Weff, out);
        } else {
            gemm32<true><<<dim3(OUT_F / 128, M / 128), 256, 0, stream>>>(
                xb, Weff, out);
        }
    } else {
        prep_kernel<<<4096, 256, 0, stream>>>(
            codes, am, Wa, Wb, x, Weff, Weff /*unused*/);
        gemm32<false><<<dim3(OUT_F / 128, M / 128), 256, 0, stream>>>(
            x, Weff, out);
    }
}